// Round 1
// baseline (445.057 us; speedup 1.0000x reference)
//
#include <hip/hip_runtime.h>

typedef __attribute__((ext_vector_type(8))) short s16x8;
typedef __attribute__((ext_vector_type(4))) float f32x4;
typedef __attribute__((ext_vector_type(8))) unsigned short u16x8;

#define GLB(p) ((const __attribute__((address_space(1))) void*)(p))
#define LDS(p) ((__attribute__((address_space(3))) void*)(p))

__device__ __forceinline__ unsigned short f2bf(float f) {
  unsigned u = __float_as_uint(f);
  u += 0x7fffu + ((u >> 16) & 1u);   // round-to-nearest-even on bf16 boundary
  return (unsigned short)(u >> 16);
}

// ---------------------------------------------------------------------------
// Kernel 1: per-row top-k (k=1024 of 2048) by |w|, ties broken by lowest
// index (matches jax.lax.top_k stable semantics). Radix-select on 43-bit
// key = (abs_bits << 11) | (2047 - i); keys are unique so exactly k survive.
// Writes masked W as bf16 into workspace.
// ---------------------------------------------------------------------------
__global__ __launch_bounds__(256) void topk_mask_kernel(
    const float* __restrict__ W, unsigned short* __restrict__ Wb) {
  __shared__ unsigned long long keys[2048];
  __shared__ int wcnt[4];
  const int tid  = threadIdx.x;
  const int lane = tid & 63;
  const int wv   = tid >> 6;
  const int row  = blockIdx.x;
  const float* wr = W + (size_t)row * 2048;

  for (int i = tid; i < 2048; i += 256) {
    unsigned a = __float_as_uint(wr[i]) & 0x7fffffffu;
    keys[i] = ((unsigned long long)a << 11) | (unsigned long long)(2047 - i);
  }
  __syncthreads();

  unsigned long long prefix = 0ull;
  int k = 1024;
  for (int bit = 42; bit >= 0; --bit) {
    const unsigned long long cand = prefix | (1ull << bit);
    const unsigned long long msk  = ~((1ull << bit) - 1ull);
    int c = 0;
    for (int i = tid; i < 2048; i += 256)
      c += ((keys[i] & msk) == cand) ? 1 : 0;
    for (int off = 32; off > 0; off >>= 1) c += __shfl_down(c, off, 64);
    if (lane == 0) wcnt[wv] = c;
    __syncthreads();
    const int total = wcnt[0] + wcnt[1] + wcnt[2] + wcnt[3];
    if (total >= k) prefix = cand; else k -= total;
    __syncthreads();
  }
  // prefix == k-th largest key; keep exactly the 1024 keys >= prefix
  for (int i = tid; i < 2048; i += 256) {
    const bool keep = keys[i] >= prefix;
    Wb[(size_t)row * 2048 + i] = keep ? f2bf(wr[i]) : (unsigned short)0;
  }
}

// ---------------------------------------------------------------------------
// Kernel 2: x fp32 -> bf16 (8 elems/thread, float4 in, 16B out)
// ---------------------------------------------------------------------------
__global__ __launch_bounds__(256) void convert_x_kernel(
    const float* __restrict__ X, unsigned short* __restrict__ Y) {
  const size_t i = ((size_t)blockIdx.x * 256 + threadIdx.x) * 8;
  const float4* xp = (const float4*)(X + i);
  const float4 a = xp[0], b = xp[1];
  u16x8 o;
  o[0] = f2bf(a.x); o[1] = f2bf(a.y); o[2] = f2bf(a.z); o[3] = f2bf(a.w);
  o[4] = f2bf(b.x); o[5] = f2bf(b.y); o[6] = f2bf(b.z); o[7] = f2bf(b.w);
  *(u16x8*)(Y + i) = o;
}

// ---------------------------------------------------------------------------
// Kernel 3: bf16 GEMM, C = A(MxK) * B(NxK)^T + bias, fp32 out.
// m97 structure: 128x128 tile, BK=32, 4 waves in 2x2, each wave 4x4 of
// 16x16x32 MFMA, global_load_lds dwordx4 staging.
// ---------------------------------------------------------------------------
__global__ __launch_bounds__(256) void gemm_bt_kernel(
    const unsigned short* __restrict__ A,   // M x K bf16
    const unsigned short* __restrict__ B,   // N x K bf16
    const float* __restrict__ bias,         // N
    float* __restrict__ C) {                // M x N fp32
  constexpr int K = 2048;
  constexpr int N = 2048;
  __shared__ __align__(16) unsigned short lA[128 * 32];
  __shared__ __align__(16) unsigned short lB[128 * 32];

  const int tid  = threadIdx.x;
  const int lane = tid & 63;
  const int wv   = tid >> 6;
  const int tile_n = blockIdx.x, tile_m = blockIdx.y;
  const int wm = (wv >> 1) * 64;
  const int wn = (wv & 1) * 64;

  f32x4 acc[4][4] = {};

  // staging: each wave issues 2 loads for A + 2 for B; 64 lanes x 16B = 16 rows
  const int srow = lane >> 2;          // row within 16-row group
  const int scol = (lane & 3) * 8;     // bf16 offset within 32-elem row
  const unsigned short* gA0 = A + (size_t)(tile_m * 128 + wv * 16 + srow) * K + scol;
  const unsigned short* gB0 = B + (size_t)(tile_n * 128 + wv * 16 + srow) * K + scol;
  unsigned short* lA0 = &lA[(wv * 16) * 32];
  unsigned short* lA1 = &lA[(64 + wv * 16) * 32];
  unsigned short* lB0 = &lB[(wv * 16) * 32];
  unsigned short* lB1 = &lB[(64 + wv * 16) * 32];
  const size_t rstep = (size_t)64 * K;

  const int fr = lane & 15;            // m (or n) within 16
  const int kg = (lane >> 4) * 8;      // k offset of this lane's 8 elems

  for (int k0 = 0; k0 < K; k0 += 32) {
    __builtin_amdgcn_global_load_lds(GLB(gA0 + k0),         LDS(lA0), 16, 0, 0);
    __builtin_amdgcn_global_load_lds(GLB(gA0 + rstep + k0), LDS(lA1), 16, 0, 0);
    __builtin_amdgcn_global_load_lds(GLB(gB0 + k0),         LDS(lB0), 16, 0, 0);
    __builtin_amdgcn_global_load_lds(GLB(gB0 + rstep + k0), LDS(lB1), 16, 0, 0);
    __syncthreads();

    s16x8 af[4], bf[4];
#pragma unroll
    for (int i = 0; i < 4; ++i)
      af[i] = *(const s16x8*)&lA[(wm + i * 16 + fr) * 32 + kg];
#pragma unroll
    for (int j = 0; j < 4; ++j)
      bf[j] = *(const s16x8*)&lB[(wn + j * 16 + fr) * 32 + kg];
#pragma unroll
    for (int i = 0; i < 4; ++i)
#pragma unroll
      for (int j = 0; j < 4; ++j)
        acc[i][j] = __builtin_amdgcn_mfma_f32_16x16x32_bf16(af[i], bf[j], acc[i][j], 0, 0, 0);
    __syncthreads();
  }

  // epilogue: C/D layout col = lane&15, row = (lane>>4)*4 + reg
  float bv[4];
#pragma unroll
  for (int j = 0; j < 4; ++j)
    bv[j] = bias[tile_n * 128 + wn + j * 16 + (lane & 15)];

  float* Cp = C + (size_t)(tile_m * 128 + wm + (lane >> 4) * 4) * N
                + tile_n * 128 + wn + (lane & 15);
#pragma unroll
  for (int i = 0; i < 4; ++i)
#pragma unroll
    for (int j = 0; j < 4; ++j)
#pragma unroll
      for (int r = 0; r < 4; ++r)
        Cp[(size_t)(i * 16 + r) * N + j * 16] = acc[i][j][r] + bv[j];
}

extern "C" void kernel_launch(void* const* d_in, const int* in_sizes, int n_in,
                              void* d_out, int out_size, void* d_ws, size_t ws_size,
                              hipStream_t stream) {
  const float* x    = (const float*)d_in[0];   // [8,2048,2048]
  const float* w    = (const float*)d_in[1];   // [2048,2048]
  const float* bias = (const float*)d_in[2];   // [2048]
  float* out = (float*)d_out;                  // [8,2048,2048]

  constexpr int M = 8 * 2048;
  constexpr int N = 2048;
  constexpr int K = 2048;

  unsigned short* xb = (unsigned short*)d_ws;        // M*K bf16 = 67.1 MB
  unsigned short* wb = xb + (size_t)M * K;           // N*K bf16 =  8.4 MB

  topk_mask_kernel<<<N, 256, 0, stream>>>(w, wb);
  convert_x_kernel<<<((size_t)M * K) / (256 * 8), 256, 0, stream>>>(x, xb);
  gemm_bt_kernel<<<dim3(N / 128, M / 128), 256, 0, stream>>>(xb, wb, bias, out);
}

// Round 2
// 406.724 us; speedup vs baseline: 1.0942x; 1.0942x over previous
//
#include <hip/hip_runtime.h>

typedef __attribute__((ext_vector_type(8))) short s16x8;
typedef __attribute__((ext_vector_type(4))) float f32x4;
typedef __attribute__((ext_vector_type(8))) unsigned short u16x8;

#define GLB(p) ((const __attribute__((address_space(1))) void*)(p))
#define LDS(p) ((__attribute__((address_space(3))) void*)(p))

__device__ __forceinline__ unsigned short f2bf(float f) {
  unsigned u = __float_as_uint(f);
  u += 0x7fffu + ((u >> 16) & 1u);   // round-to-nearest-even on bf16 boundary
  return (unsigned short)(u >> 16);
}

// ---------------------------------------------------------------------------
// Kernel 1: per-row top-k (k=1024 of 2048) by |w|, exact, ties broken by
// lowest index (jax.lax.top_k stable semantics).
// 3-round histogram radix select (12+10+10 bits) on 32-bit abs keys held in
// registers; tie resolution via block-ordered scan of ==T flags.
// Writes masked W as bf16 into workspace.
// ---------------------------------------------------------------------------
__global__ __launch_bounds__(256) void topk_mask_kernel(
    const float* __restrict__ W, unsigned short* __restrict__ Wb) {
  __shared__ int hist[4096];        // 16 KB, reused across rounds
  __shared__ int scanres[2];        // {selected digit, new rem}
  __shared__ int wsum[4];
  const int tid  = threadIdx.x;
  const int lane = tid & 63;
  const int wv   = tid >> 6;
  const int row  = blockIdx.x;
  const float* wr = W + (size_t)row * 2048;

  // Thread t owns contiguous elems [8t, 8t+8) — index order == thread order.
  const float4 v0 = *(const float4*)(wr + tid * 8);
  const float4 v1 = *(const float4*)(wr + tid * 8 + 4);
  float val[8] = {v0.x, v0.y, v0.z, v0.w, v1.x, v1.y, v1.z, v1.w};
  unsigned key[8];
#pragma unroll
  for (int e = 0; e < 8; ++e) key[e] = __float_as_uint(val[e]) & 0x7fffffffu;

  unsigned prefix = 0;
  int rem = 1024;   // invariant: 1 <= rem <= #elems matching prefix

  // ---- Round 0: bits [31:20], 4096 bins ----
  for (int i = tid; i < 4096; i += 256) hist[i] = 0;
  __syncthreads();
#pragma unroll
  for (int e = 0; e < 8; ++e) atomicAdd(&hist[key[e] >> 20], 1);
  __syncthreads();
  if (wv == 0) {
    const int base = 4096 - (lane + 1) * 64;   // lane 0 = highest bins
    int s = 0;
    for (int b = 0; b < 64; ++b) s += hist[base + b];
    int cum = s;
#pragma unroll
    for (int off = 1; off < 64; off <<= 1) {
      int o = __shfl_up(cum, off, 64);
      if (lane >= off) cum += o;
    }
    const int cumex = cum - s;
    if (cumex < rem && rem <= cum) {           // unique lane
      int running = cumex;
      for (int b = 63; b >= 0; --b) {
        int h = hist[base + b];
        if (running + h >= rem) { scanres[0] = base + b; scanres[1] = rem - running; break; }
        running += h;
      }
    }
  }
  __syncthreads();
  prefix = ((unsigned)scanres[0]) << 20;
  rem = scanres[1];
  __syncthreads();

  // ---- Round 1: bits [19:10], 1024 bins ----
  for (int i = tid; i < 1024; i += 256) hist[i] = 0;
  __syncthreads();
#pragma unroll
  for (int e = 0; e < 8; ++e)
    if ((key[e] >> 20) == (prefix >> 20)) atomicAdd(&hist[(key[e] >> 10) & 1023], 1);
  __syncthreads();
  if (wv == 0) {
    const int base = 1024 - (lane + 1) * 16;
    int s = 0;
    for (int b = 0; b < 16; ++b) s += hist[base + b];
    int cum = s;
#pragma unroll
    for (int off = 1; off < 64; off <<= 1) {
      int o = __shfl_up(cum, off, 64);
      if (lane >= off) cum += o;
    }
    const int cumex = cum - s;
    if (cumex < rem && rem <= cum) {
      int running = cumex;
      for (int b = 15; b >= 0; --b) {
        int h = hist[base + b];
        if (running + h >= rem) { scanres[0] = base + b; scanres[1] = rem - running; break; }
        running += h;
      }
    }
  }
  __syncthreads();
  prefix |= ((unsigned)scanres[0]) << 10;
  rem = scanres[1];
  __syncthreads();

  // ---- Round 2: bits [9:0], 1024 bins ----
  for (int i = tid; i < 1024; i += 256) hist[i] = 0;
  __syncthreads();
#pragma unroll
  for (int e = 0; e < 8; ++e)
    if ((key[e] >> 10) == (prefix >> 10)) atomicAdd(&hist[key[e] & 1023], 1);
  __syncthreads();
  if (wv == 0) {
    const int base = 1024 - (lane + 1) * 16;
    int s = 0;
    for (int b = 0; b < 16; ++b) s += hist[base + b];
    int cum = s;
#pragma unroll
    for (int off = 1; off < 64; off <<= 1) {
      int o = __shfl_up(cum, off, 64);
      if (lane >= off) cum += o;
    }
    const int cumex = cum - s;
    if (cumex < rem && rem <= cum) {
      int running = cumex;
      for (int b = 15; b >= 0; --b) {
        int h = hist[base + b];
        if (running + h >= rem) { scanres[0] = base + b; scanres[1] = rem - running; break; }
        running += h;
      }
    }
  }
  __syncthreads();
  const unsigned T = prefix | (unsigned)scanres[0];   // exact k-th largest abs
  rem = scanres[1];                                   // # of ==T to keep (lowest index first)

  // ---- Tie resolution: block-ordered exclusive scan of ==T counts ----
  int eqcnt = 0;
#pragma unroll
  for (int e = 0; e < 8; ++e) eqcnt += (key[e] == T) ? 1 : 0;
  int c = eqcnt;
#pragma unroll
  for (int off = 1; off < 64; off <<= 1) {
    int o = __shfl_up(c, off, 64);
    if (lane >= off) c += o;
  }
  if (lane == 63) wsum[wv] = c;
  __syncthreads();
  int wavebase = 0;
  for (int j = 0; j < wv; ++j) wavebase += wsum[j];
  const int myex = wavebase + c - eqcnt;   // exclusive prefix of eq over lower indices

  u16x8 o;
  int r = 0;
#pragma unroll
  for (int e = 0; e < 8; ++e) {
    const bool iseq = (key[e] == T);
    const bool keep = (key[e] > T) || (iseq && (myex + r) < rem);
    r += iseq ? 1 : 0;
    o[e] = keep ? f2bf(val[e]) : (unsigned short)0;
  }
  *(u16x8*)(Wb + (size_t)row * 2048 + tid * 8) = o;
}

// ---------------------------------------------------------------------------
// Kernel 2: x fp32 -> bf16 (8 elems/thread, float4 in, 16B out)
// ---------------------------------------------------------------------------
__global__ __launch_bounds__(256) void convert_x_kernel(
    const float* __restrict__ X, unsigned short* __restrict__ Y) {
  const size_t i = ((size_t)blockIdx.x * 256 + threadIdx.x) * 8;
  const float4* xp = (const float4*)(X + i);
  const float4 a = xp[0], b = xp[1];
  u16x8 o;
  o[0] = f2bf(a.x); o[1] = f2bf(a.y); o[2] = f2bf(a.z); o[3] = f2bf(a.w);
  o[4] = f2bf(b.x); o[5] = f2bf(b.y); o[6] = f2bf(b.z); o[7] = f2bf(b.w);
  *(u16x8*)(Y + i) = o;
}

// ---------------------------------------------------------------------------
// Kernel 3: bf16 GEMM, C = A(MxK) * B(NxK)^T + bias, fp32 out.
// m97 structure: 128x128 tile, BK=32, 4 waves in 2x2, each wave 4x4 of
// 16x16x32 MFMA, global_load_lds dwordx4 staging. (Unchanged this round.)
// ---------------------------------------------------------------------------
__global__ __launch_bounds__(256) void gemm_bt_kernel(
    const unsigned short* __restrict__ A,   // M x K bf16
    const unsigned short* __restrict__ B,   // N x K bf16
    const float* __restrict__ bias,         // N
    float* __restrict__ C) {                // M x N fp32
  constexpr int K = 2048;
  constexpr int N = 2048;
  __shared__ __align__(16) unsigned short lA[128 * 32];
  __shared__ __align__(16) unsigned short lB[128 * 32];

  const int tid  = threadIdx.x;
  const int lane = tid & 63;
  const int wv   = tid >> 6;
  const int tile_n = blockIdx.x, tile_m = blockIdx.y;
  const int wm = (wv >> 1) * 64;
  const int wn = (wv & 1) * 64;

  f32x4 acc[4][4] = {};

  const int srow = lane >> 2;          // row within 16-row group
  const int scol = (lane & 3) * 8;     // bf16 offset within 32-elem row
  const unsigned short* gA0 = A + (size_t)(tile_m * 128 + wv * 16 + srow) * K + scol;
  const unsigned short* gB0 = B + (size_t)(tile_n * 128 + wv * 16 + srow) * K + scol;
  unsigned short* lA0 = &lA[(wv * 16) * 32];
  unsigned short* lA1 = &lA[(64 + wv * 16) * 32];
  unsigned short* lB0 = &lB[(wv * 16) * 32];
  unsigned short* lB1 = &lB[(64 + wv * 16) * 32];
  const size_t rstep = (size_t)64 * K;

  const int fr = lane & 15;            // m (or n) within 16
  const int kg = (lane >> 4) * 8;      // k offset of this lane's 8 elems

  for (int k0 = 0; k0 < K; k0 += 32) {
    __builtin_amdgcn_global_load_lds(GLB(gA0 + k0),         LDS(lA0), 16, 0, 0);
    __builtin_amdgcn_global_load_lds(GLB(gA0 + rstep + k0), LDS(lA1), 16, 0, 0);
    __builtin_amdgcn_global_load_lds(GLB(gB0 + k0),         LDS(lB0), 16, 0, 0);
    __builtin_amdgcn_global_load_lds(GLB(gB0 + rstep + k0), LDS(lB1), 16, 0, 0);
    __syncthreads();

    s16x8 af[4], bf[4];
#pragma unroll
    for (int i = 0; i < 4; ++i)
      af[i] = *(const s16x8*)&lA[(wm + i * 16 + fr) * 32 + kg];
#pragma unroll
    for (int j = 0; j < 4; ++j)
      bf[j] = *(const s16x8*)&lB[(wn + j * 16 + fr) * 32 + kg];
#pragma unroll
    for (int i = 0; i < 4; ++i)
#pragma unroll
      for (int j = 0; j < 4; ++j)
        acc[i][j] = __builtin_amdgcn_mfma_f32_16x16x32_bf16(af[i], bf[j], acc[i][j], 0, 0, 0);
    __syncthreads();
  }

  // epilogue: C/D layout col = lane&15, row = (lane>>4)*4 + reg
  float bv[4];
#pragma unroll
  for (int j = 0; j < 4; ++j)
    bv[j] = bias[tile_n * 128 + wn + j * 16 + (lane & 15)];

  float* Cp = C + (size_t)(tile_m * 128 + wm + (lane >> 4) * 4) * N
                + tile_n * 128 + wn + (lane & 15);
#pragma unroll
  for (int i = 0; i < 4; ++i)
#pragma unroll
    for (int j = 0; j < 4; ++j)
#pragma unroll
      for (int r = 0; r < 4; ++r)
        Cp[(size_t)(i * 16 + r) * N + j * 16] = acc[i][j][r] + bv[j];
}

extern "C" void kernel_launch(void* const* d_in, const int* in_sizes, int n_in,
                              void* d_out, int out_size, void* d_ws, size_t ws_size,
                              hipStream_t stream) {
  const float* x    = (const float*)d_in[0];   // [8,2048,2048]
  const float* w    = (const float*)d_in[1];   // [2048,2048]
  const float* bias = (const float*)d_in[2];   // [2048]
  float* out = (float*)d_out;                  // [8,2048,2048]

  constexpr int M = 8 * 2048;
  constexpr int N = 2048;
  constexpr int K = 2048;

  unsigned short* xb = (unsigned short*)d_ws;        // M*K bf16 = 67.1 MB
  unsigned short* wb = xb + (size_t)M * K;           // N*K bf16 =  8.4 MB

  topk_mask_kernel<<<N, 256, 0, stream>>>(w, wb);
  convert_x_kernel<<<((size_t)M * K) / (256 * 8), 256, 0, stream>>>(x, xb);
  gemm_bt_kernel<<<dim3(N / 128, M / 128), 256, 0, stream>>>(xb, wb, bias, out);
}

// Round 3
// 377.671 us; speedup vs baseline: 1.1784x; 1.0769x over previous
//
#include <hip/hip_runtime.h>

typedef __attribute__((ext_vector_type(8))) short s16x8;
typedef __attribute__((ext_vector_type(4))) float f32x4;
typedef __attribute__((ext_vector_type(8))) unsigned short u16x8;

#define GLB(p) ((const __attribute__((address_space(1))) void*)(p))
#define LDS(p) ((__attribute__((address_space(3))) void*)(p))

__device__ __forceinline__ unsigned short f2bf(float f) {
  unsigned u = __float_as_uint(f);
  u += 0x7fffu + ((u >> 16) & 1u);   // round-to-nearest-even on bf16 boundary
  return (unsigned short)(u >> 16);
}

// ---------------------------------------------------------------------------
// Kernel 1 (merged): blocks [0,2048) do per-row top-k masking of W;
// blocks [2048, 2048+16384) convert x fp32->bf16. Independent work fused
// into one dispatch so both fill the machine together.
// ---------------------------------------------------------------------------
__global__ __launch_bounds__(256) void prep_kernel(
    const float* __restrict__ W, unsigned short* __restrict__ Wb,
    const float* __restrict__ X, unsigned short* __restrict__ Xb) {
  __shared__ int hist[4096];
  __shared__ int scanres[2];
  __shared__ int wsum[4];
  const int tid  = threadIdx.x;

  if (blockIdx.x >= 2048) {
    // ---- convert path ----
    const size_t i = ((size_t)(blockIdx.x - 2048) * 256 + tid) * 8;
    const float4* xp = (const float4*)(X + i);
    const float4 a = xp[0], b = xp[1];
    u16x8 o;
    o[0] = f2bf(a.x); o[1] = f2bf(a.y); o[2] = f2bf(a.z); o[3] = f2bf(a.w);
    o[4] = f2bf(b.x); o[5] = f2bf(b.y); o[6] = f2bf(b.z); o[7] = f2bf(b.w);
    *(u16x8*)(Xb + i) = o;
    return;
  }

  // ---- top-k path: exact k=1024 of 2048 by |w|, lowest-index tie-break ----
  const int lane = tid & 63;
  const int wv   = tid >> 6;
  const int row  = blockIdx.x;
  const float* wr = W + (size_t)row * 2048;

  const float4 v0 = *(const float4*)(wr + tid * 8);
  const float4 v1 = *(const float4*)(wr + tid * 8 + 4);
  float val[8] = {v0.x, v0.y, v0.z, v0.w, v1.x, v1.y, v1.z, v1.w};
  unsigned key[8];
#pragma unroll
  for (int e = 0; e < 8; ++e) key[e] = __float_as_uint(val[e]) & 0x7fffffffu;

  unsigned prefix = 0;
  int rem = 1024;

  // Round 0: bits [31:20], 4096 bins
  for (int i = tid; i < 4096; i += 256) hist[i] = 0;
  __syncthreads();
#pragma unroll
  for (int e = 0; e < 8; ++e) atomicAdd(&hist[key[e] >> 20], 1);
  __syncthreads();
  if (wv == 0) {
    const int base = 4096 - (lane + 1) * 64;
    int s = 0;
    for (int b = 0; b < 64; ++b) s += hist[base + b];
    int cum = s;
#pragma unroll
    for (int off = 1; off < 64; off <<= 1) {
      int o = __shfl_up(cum, off, 64);
      if (lane >= off) cum += o;
    }
    const int cumex = cum - s;
    if (cumex < rem && rem <= cum) {
      int running = cumex;
      for (int b = 63; b >= 0; --b) {
        int h = hist[base + b];
        if (running + h >= rem) { scanres[0] = base + b; scanres[1] = rem - running; break; }
        running += h;
      }
    }
  }
  __syncthreads();
  prefix = ((unsigned)scanres[0]) << 20;
  rem = scanres[1];
  __syncthreads();

  // Round 1: bits [19:10], 1024 bins
  for (int i = tid; i < 1024; i += 256) hist[i] = 0;
  __syncthreads();
#pragma unroll
  for (int e = 0; e < 8; ++e)
    if ((key[e] >> 20) == (prefix >> 20)) atomicAdd(&hist[(key[e] >> 10) & 1023], 1);
  __syncthreads();
  if (wv == 0) {
    const int base = 1024 - (lane + 1) * 16;
    int s = 0;
    for (int b = 0; b < 16; ++b) s += hist[base + b];
    int cum = s;
#pragma unroll
    for (int off = 1; off < 64; off <<= 1) {
      int o = __shfl_up(cum, off, 64);
      if (lane >= off) cum += o;
    }
    const int cumex = cum - s;
    if (cumex < rem && rem <= cum) {
      int running = cumex;
      for (int b = 15; b >= 0; --b) {
        int h = hist[base + b];
        if (running + h >= rem) { scanres[0] = base + b; scanres[1] = rem - running; break; }
        running += h;
      }
    }
  }
  __syncthreads();
  prefix |= ((unsigned)scanres[0]) << 10;
  rem = scanres[1];
  __syncthreads();

  // Round 2: bits [9:0], 1024 bins
  for (int i = tid; i < 1024; i += 256) hist[i] = 0;
  __syncthreads();
#pragma unroll
  for (int e = 0; e < 8; ++e)
    if ((key[e] >> 10) == (prefix >> 10)) atomicAdd(&hist[key[e] & 1023], 1);
  __syncthreads();
  if (wv == 0) {
    const int base = 1024 - (lane + 1) * 16;
    int s = 0;
    for (int b = 0; b < 16; ++b) s += hist[base + b];
    int cum = s;
#pragma unroll
    for (int off = 1; off < 64; off <<= 1) {
      int o = __shfl_up(cum, off, 64);
      if (lane >= off) cum += o;
    }
    const int cumex = cum - s;
    if (cumex < rem && rem <= cum) {
      int running = cumex;
      for (int b = 15; b >= 0; --b) {
        int h = hist[base + b];
        if (running + h >= rem) { scanres[0] = base + b; scanres[1] = rem - running; break; }
        running += h;
      }
    }
  }
  __syncthreads();
  const unsigned T = prefix | (unsigned)scanres[0];
  rem = scanres[1];

  // Tie resolution: block-ordered exclusive scan of ==T counts
  int eqcnt = 0;
#pragma unroll
  for (int e = 0; e < 8; ++e) eqcnt += (key[e] == T) ? 1 : 0;
  int c = eqcnt;
#pragma unroll
  for (int off = 1; off < 64; off <<= 1) {
    int o = __shfl_up(c, off, 64);
    if (lane >= off) c += o;
  }
  if (lane == 63) wsum[wv] = c;
  __syncthreads();
  int wavebase = 0;
  for (int j = 0; j < wv; ++j) wavebase += wsum[j];
  const int myex = wavebase + c - eqcnt;

  u16x8 o;
  int r = 0;
#pragma unroll
  for (int e = 0; e < 8; ++e) {
    const bool iseq = (key[e] == T);
    const bool keep = (key[e] > T) || (iseq && (myex + r) < rem);
    r += iseq ? 1 : 0;
    o[e] = keep ? f2bf(val[e]) : (unsigned short)0;
  }
  *(u16x8*)(Wb + (size_t)row * 2048 + tid * 8) = o;
}

// ---------------------------------------------------------------------------
// Kernel 2: bf16 GEMM, C = A(MxK) * B(NxK)^T + bias, fp32 out.
// BK=64 (32 MFMA per barrier), XOR-swizzled LDS placement (bank-conflict
// reduction), 4x4 supertile block remap for L2 locality.
// LDS logical: tile[row][64]; 16B unit u of row r stored at phys unit
// (u ^ (r&7)). Swizzle applied via the global src address during
// global_load_lds staging (dest is always base + lane*16).
// ---------------------------------------------------------------------------
__global__ __launch_bounds__(256) void gemm_bt_kernel(
    const unsigned short* __restrict__ A,   // M x K bf16
    const unsigned short* __restrict__ B,   // N x K bf16
    const float* __restrict__ bias,         // N
    float* __restrict__ C) {                // M x N fp32
  constexpr int K = 2048;
  constexpr int N = 2048;
  __shared__ __align__(16) unsigned short lA[128 * 64];  // 16 KB
  __shared__ __align__(16) unsigned short lB[128 * 64];  // 16 KB

  const int tid  = threadIdx.x;
  const int lane = tid & 63;
  const int wv   = tid >> 6;

  // 4x4 supertile remap: 16 consecutive linear blocks cover a 4(m)x4(n)
  // patch -> A/B tile working set ~4 MB, fits one XCD L2.
  const int lin = blockIdx.y * 16 + blockIdx.x;
  const int st = lin >> 4, wi = lin & 15;
  const int tile_n = (st & 3) * 4 + (wi & 3);
  const int tile_m = (st >> 2) * 4 + (wi >> 2);

  const int wm = (wv >> 1) * 64;
  const int wn = (wv & 1) * 64;

  f32x4 acc[4][4] = {};

  // staging: per wave 4 issues for A + 4 for B per K-iter.
  // lane -> row offset (lane>>3), phys unit (lane&7);
  // global col unit = (lane&7) ^ (lane>>3)  [logical unit at that phys slot]
  const int srow = lane >> 3;
  const int sxor = ((lane & 7) ^ srow) * 8;
  const unsigned short* gA0 = A + (size_t)(tile_m * 128 + wv * 8 + srow) * K + sxor;
  const unsigned short* gB0 = B + (size_t)(tile_n * 128 + wv * 8 + srow) * K + sxor;
  const size_t rstep = (size_t)32 * K;
  unsigned short* lAq[4];
  unsigned short* lBq[4];
#pragma unroll
  for (int q = 0; q < 4; ++q) {
    lAq[q] = &lA[(q * 32 + wv * 8) * 64];
    lBq[q] = &lB[(q * 32 + wv * 8) * 64];
  }

  // fragment read offsets: logical kg8 = kk*4 + qw; phys unit = kg8 ^ (fr&7)
  const int fr = lane & 15;
  const int qw = lane >> 4;
  const int x0 = ((qw ^ (fr & 7))) * 8;     // kk = 0
  const int x1 = x0 ^ 32;                    // kk = 1 (unit ^ 4 -> elems ^ 32)
  const unsigned short* la_f = &lA[(wm + fr) * 64];
  const unsigned short* lb_f = &lB[(wn + fr) * 64];

  for (int k0 = 0; k0 < K; k0 += 64) {
#pragma unroll
    for (int q = 0; q < 4; ++q) {
      __builtin_amdgcn_global_load_lds(GLB(gA0 + q * rstep + k0), LDS(lAq[q]), 16, 0, 0);
      __builtin_amdgcn_global_load_lds(GLB(gB0 + q * rstep + k0), LDS(lBq[q]), 16, 0, 0);
    }
    __syncthreads();

#pragma unroll
    for (int kk = 0; kk < 2; ++kk) {
      const int xo = kk ? x1 : x0;
      s16x8 af[4], bf[4];
#pragma unroll
      for (int i = 0; i < 4; ++i)
        af[i] = *(const s16x8*)&la_f[i * 16 * 64 + xo];
#pragma unroll
      for (int j = 0; j < 4; ++j)
        bf[j] = *(const s16x8*)&lb_f[j * 16 * 64 + xo];
#pragma unroll
      for (int i = 0; i < 4; ++i)
#pragma unroll
        for (int j = 0; j < 4; ++j)
          acc[i][j] = __builtin_amdgcn_mfma_f32_16x16x32_bf16(af[i], bf[j], acc[i][j], 0, 0, 0);
    }
    __syncthreads();
  }

  // epilogue: C/D layout col = lane&15, row = (lane>>4)*4 + reg
  float bv[4];
#pragma unroll
  for (int j = 0; j < 4; ++j)
    bv[j] = bias[tile_n * 128 + wn + j * 16 + (lane & 15)];

  float* Cp = C + (size_t)(tile_m * 128 + wm + (lane >> 4) * 4) * N
                + tile_n * 128 + wn + (lane & 15);
#pragma unroll
  for (int i = 0; i < 4; ++i)
#pragma unroll
    for (int j = 0; j < 4; ++j)
#pragma unroll
      for (int r = 0; r < 4; ++r)
        Cp[(size_t)(i * 16 + r) * N + j * 16] = acc[i][j][r] + bv[j];
}

extern "C" void kernel_launch(void* const* d_in, const int* in_sizes, int n_in,
                              void* d_out, int out_size, void* d_ws, size_t ws_size,
                              hipStream_t stream) {
  const float* x    = (const float*)d_in[0];   // [8,2048,2048]
  const float* w    = (const float*)d_in[1];   // [2048,2048]
  const float* bias = (const float*)d_in[2];   // [2048]
  float* out = (float*)d_out;                  // [8,2048,2048]

  constexpr int M = 8 * 2048;
  constexpr int N = 2048;
  constexpr int K = 2048;

  unsigned short* xb = (unsigned short*)d_ws;        // M*K bf16 = 67.1 MB
  unsigned short* wb = xb + (size_t)M * K;           // N*K bf16 =  8.4 MB

  const int conv_blocks = ((size_t)M * K) / (256 * 8);
  prep_kernel<<<2048 + conv_blocks, 256, 0, stream>>>(w, wb, x, xb);
  gemm_bt_kernel<<<dim3(N / 128, M / 128), 256, 0, stream>>>(xb, wb, bias, out);
}